// Round 5
// baseline (385.726 us; speedup 1.0000x reference)
//
#include <hip/hip_runtime.h>

// NURBS cubic surface eval: S*F=32 surfaces, 32x32 CPs, degree 3, uniform
// clamped knots. Outputs: pt [SF,P,3] and normalized normals [SF,P,3].
//
// Round-5 structure. Evidence so far:
//  - R2 (1024thr, 1pt/thr, float4 LDS windows, VGPR 28, 32 waves/CU): 76us.
//  - R3: runtime-indexed private arrays -> scratch spill, 7x regression.
//  - R4: 2pt/thread at 512thr: 24 waves/CU, +9us vs R2 -> wave count beats
//    per-thread ILP when ILP costs registers.
//  - Pipe model of R2: VALU ~20us + LDS ~28us + HBM ~26us ~= 76us serial sum,
//    zero overlap. Lever = overlap, not instruction count.
// This round: persistent blocks (grid 8x32 = 256 = exactly 2/CU) with a
// grid-stride loop and SOFTWARE-PREFETCHED uv: the ~900-cycle ev load no
// longer heads each point's dependency chain - it overlaps the previous
// point's basis+LDS+contraction. Staging runs once per block (256x vs 3136x).
// launch_bounds(1024,8) pins VGPR<=64 so 2 blocks/CU always fit.

#define NCP 32

// Cubic B-spline basis values B0[0..3] and UNSCALED deriv shape D[0..3] on
// the uniform clamped grid, knot-interval units. U = u*29 in [0,29).
// D = true_deriv / (3*29); uniform factor cancels in cross+normalize.
// (Correctness proven in R3/R4 runs.)
__device__ __forceinline__ void basis3u(float U, int& A, float B0[4], float D[4])
{
    float Af = floorf(U);
    A = (int)Af;
    float t  = U - Af;                 // local coord in [0,1)
    float c1 = fminf(Af, 1.0f);
    float c2 = fminf(Af, 2.0f);
    float gg = 29.0f - Af;
    float e1 = fminf(gg, 2.0f);
    float e2 = fminf(gg, 3.0f);
    float L1 = t, L2 = t + c1, L3 = t + c2;
    float R1 = 1.0f - t, R2 = e1 - t, R3 = e2 - t;
    float q20 = (Af < 1.0f) ? 1.0f : 0.5f;
    float q21 = (gg < 2.0f) ? 1.0f : 0.5f;
    float q30 = (Af < 1.0f) ? 1.0f : ((Af < 2.0f) ? 0.5f : (1.0f / 3.0f));
    float q31 = ((Af < 1.0f) || (gg < 2.0f)) ? 0.5f : (1.0f / 3.0f);
    float q32 = (gg < 2.0f) ? 1.0f : ((gg < 3.0f) ? 0.5f : (1.0f / 3.0f));
    float ta  = R1 * q20;
    float n02 = R1 * ta;
    float sv  = L2 * ta;
    float tb  = L1 * q21;
    float n12 = fmaf(R2, tb, sv);
    float n22 = L1 * tb;
    float t0 = n02 * q30;
    B0[0] = R1 * t0;
    sv = L3 * t0;
    float t1 = n12 * q31;
    B0[1] = fmaf(R2, t1, sv);
    sv = L2 * t1;
    float t2 = n22 * q32;
    B0[2] = fmaf(R3, t2, sv);
    B0[3] = L1 * t2;
    D[0] = -t0;
    D[1] = t0 - t1;
    D[2] = t1 - t2;
    D[3] = t2;
}

__global__ __launch_bounds__(1024, 8) void nurbs_eval_kernel(
    const float2* __restrict__ ev,   // [SF*P] (u,v)
    const float*  __restrict__ cp,   // [SF*32*32*3]
    float* __restrict__ out_pt,      // [SF*P*3]
    float* __restrict__ out_nrm,     // [SF*P*3]
    int P)
{
    // win[(row*32+c)*3+q]: CPs [row][c..c+3] xyz-interleaved in 3 float4s
    // (R2-proven layout; av stride 12 dwords -> 8 bank phases, row stride 384)
    __shared__ float4 win[NCP * NCP * 3];   // 48 KB -> 2 blocks/CU

    const int sf = blockIdx.y;
    {   // stage once per (persistent) block: 928 records, one pass
        const float* g = cp + (size_t)sf * (NCP * NCP * 3);
        const int idx = threadIdx.x;
        if (idx < NCP * 29) {
            int row = idx / 29;           // magic-mul, staging only
            int c   = idx - row * 29;
            const float* r = g + (row * NCP + c) * 3;
            int w = (row * NCP + c) * 3;
            win[w + 0] = make_float4(r[0], r[1], r[2],  r[3]);
            win[w + 1] = make_float4(r[4], r[5], r[6],  r[7]);
            win[w + 2] = make_float4(r[8], r[9], r[10], r[11]);
        }
    }
    __syncthreads();

    const float2* evp = ev + (size_t)sf * P;
    float* op = out_pt  + (size_t)sf * P * 3;
    float* on = out_nrm + (size_t)sf * P * 3;

    const int stride = gridDim.x * 1024;     // 8192
    int i = blockIdx.x * 1024 + threadIdx.x; // < stride <= P: every thread live
    float2 uv = evp[i];                      // prime the pipeline

    while (true) {
        // ---- prefetch next point's uv (overlaps this point's compute) ----
        const int inext = i + stride;
        const bool more = inext < P;
        float2 uvn = uv;
        if (more) uvn = evp[inext];

        // ---- evaluate current point ----
        int au, av;
        float B0u[4], B1u[4], B0v[4], B1v[4];
        basis3u(uv.x * 29.0f, au, B0u, B1u);
        basis3u(uv.y * 29.0f, av, B0v, B1v);
        const float bv0 = B0v[0], bv1 = B0v[1], bv2 = B0v[2], bv3 = B0v[3];
        const float dv0 = B1v[0], dv1 = B1v[1], dv2 = B1v[2], dv3 = B1v[3];

        float sx = 0.f, sy = 0.f, sz = 0.f;
        float ux = 0.f, uy = 0.f, uz = 0.f;
        float vx = 0.f, vy = 0.f, vz = 0.f;
        const int base = (au * NCP + av) * 3;
#pragma unroll
        for (int r = 0; r < 4; ++r) {
            const float4 q0 = win[base + r * (NCP * 3) + 0];
            const float4 q1 = win[base + r * (NCP * 3) + 1];
            const float4 q2 = win[base + r * (NCP * 3) + 2];
            const float cx0 = q0.x, cy0 = q0.y, cz0 = q0.z;
            const float cx1 = q0.w, cy1 = q1.x, cz1 = q1.y;
            const float cx2 = q1.z, cy2 = q1.w, cz2 = q2.x;
            const float cx3 = q2.y, cy3 = q2.z, cz3 = q2.w;
            float rpx = fmaf(bv3, cx3, fmaf(bv2, cx2, fmaf(bv1, cx1, bv0 * cx0)));
            float rpy = fmaf(bv3, cy3, fmaf(bv2, cy2, fmaf(bv1, cy1, bv0 * cy0)));
            float rpz = fmaf(bv3, cz3, fmaf(bv2, cz2, fmaf(bv1, cz1, bv0 * cz0)));
            float rvx = fmaf(dv3, cx3, fmaf(dv2, cx2, fmaf(dv1, cx1, dv0 * cx0)));
            float rvy = fmaf(dv3, cy3, fmaf(dv2, cy2, fmaf(dv1, cy1, dv0 * cy0)));
            float rvz = fmaf(dv3, cz3, fmaf(dv2, cz2, fmaf(dv1, cz1, dv0 * cz0)));
            const float bu = B0u[r], du = B1u[r];
            sx = fmaf(bu, rpx, sx); sy = fmaf(bu, rpy, sy); sz = fmaf(bu, rpz, sz);
            ux = fmaf(du, rpx, ux); uy = fmaf(du, rpy, uy); uz = fmaf(du, rpz, uz);
            vx = fmaf(bu, rvx, vx); vy = fmaf(bu, rvy, vy); vz = fmaf(bu, rvz, vz);
        }

        float cxn = uy * vz - uz * vy;
        float cyn = uz * vx - ux * vz;
        float czn = ux * vy - uy * vx;
        float d   = fmaf(cxn, cxn, fmaf(cyn, cyn, czn * czn));
        float len = __builtin_amdgcn_sqrtf(d);
        float inv = __builtin_amdgcn_rcpf(len + 1e-12f);

        const size_t o = (size_t)i * 3;
        op[o + 0] = sx;        op[o + 1] = sy;        op[o + 2] = sz;
        on[o + 0] = cxn * inv; on[o + 1] = cyn * inv; on[o + 2] = czn * inv;

        if (!more) break;
        i = inext;
        uv = uvn;
    }
}

extern "C" void kernel_launch(void* const* d_in, const int* in_sizes, int n_in,
                              void* d_out, int out_size, void* d_ws, size_t ws_size,
                              hipStream_t stream) {
    (void)n_in; (void)d_ws; (void)ws_size; (void)out_size;
    const int SF = in_sizes[1] / (NCP * NCP * 3);   // S*F = 32
    const int P  = in_sizes[0] / (SF * 2);          // 200000
    const int N  = SF * P;                          // 6.4M points

    const float2* ev = (const float2*)d_in[0];
    const float*  cp = (const float*)d_in[1];
    float* out_pt  = (float*)d_out;
    float* out_nrm = (float*)d_out + (size_t)N * 3;

    // 256 persistent blocks = exactly 2 per CU (1024 thr, 48 KB LDS, VGPR<=64)
    dim3 block(1024);
    dim3 grid(8, SF);
    nurbs_eval_kernel<<<grid, block, 0, stream>>>(ev, cp, out_pt, out_nrm, P);
}